// Round 1
// baseline (1114.899 us; speedup 1.0000x reference)
//
#include <hip/hip_runtime.h>

#define NN 100000
#define EE 1250000
#define HH 64
#define BB 256
#define CC 2

// ---------------------------------------------------------------------------
// Index dtype canonicalization: reference declares int64, harness docs say
// int32. Detect on device: int64 values < 2^31 -> every odd 32-bit word is 0.
// ---------------------------------------------------------------------------
__global__ void detect_i64(const int* __restrict__ raw, int* __restrict__ flag) {
    __shared__ int nonzero;
    if (threadIdx.x == 0) nonzero = 0;
    __syncthreads();
    int any = 0;
#pragma unroll
    for (int i = 0; i < 4; ++i) {
        int idx = 2 * (threadIdx.x + i * 256) + 1;   // odd words, safe in both layouts
        if (raw[idx] != 0) any = 1;
    }
    if (any) atomicOr(&nonzero, 1);
    __syncthreads();
    if (threadIdx.x == 0) *flag = nonzero ? 0 : 1;   // 1 => int64
}

__global__ void convert_edges(const int* __restrict__ raw, int* __restrict__ src,
                              int* __restrict__ dst, const int* __restrict__ flag) {
    int e = blockIdx.x * 256 + threadIdx.x;
    if (e >= EE) return;
    int f = *flag;
    src[e] = f ? raw[2 * e]        : raw[e];
    dst[e] = f ? raw[2 * (EE + e)] : raw[EE + e];
}

__global__ void convert_batch(const int* __restrict__ raw, int* __restrict__ out,
                              const int* __restrict__ flag) {
    int n = blockIdx.x * 256 + threadIdx.x;
    if (n >= NN) return;
    out[n] = (*flag) ? raw[2 * n] : raw[n];
}

// ---------------------------------------------------------------------------
// Degree (dst-side, +1 self loop) and normalization
// ---------------------------------------------------------------------------
__global__ void deg_kernel(const int* __restrict__ dst, float* __restrict__ deg) {
    int e = blockIdx.x * 256 + threadIdx.x;
    if (e < EE) atomicAdd(&deg[dst[e]], 1.0f);
}

__global__ void dinv_kernel(const float* __restrict__ deg, float* __restrict__ dinv) {
    int n = blockIdx.x * 256 + threadIdx.x;
    if (n < NN) dinv[n] = rsqrtf(deg[n] + 1.0f);
}

__global__ void norm_kernel(const int* __restrict__ src, const int* __restrict__ dst,
                            const float* __restrict__ dinv, float* __restrict__ norm) {
    int e = blockIdx.x * 256 + threadIdx.x;
    if (e < EE) norm[e] = dinv[src[e]] * dinv[dst[e]];
}

// ---------------------------------------------------------------------------
// h = (relu?)X @ W ;  Agg_init = dinv^2 * h + bias   (fused)
// block = 256 threads = 4 rows x 64 cols; W staged in LDS (16 KB)
// ---------------------------------------------------------------------------
__global__ __launch_bounds__(256) void gemm_init(
        const float* __restrict__ X, const float* __restrict__ W,
        const float* __restrict__ bias, const float* __restrict__ dinv,
        float* __restrict__ Hout, float* __restrict__ Agg, int relu_in) {
    __shared__ float Ws[64 * 64];
    __shared__ float Xs[4 * 64];
    int tid = threadIdx.x;
    for (int i = tid; i < 64 * 64; i += 256) Ws[i] = W[i];

    int r = tid >> 6, c = tid & 63;
    int row = blockIdx.x * 4 + r;        // N divisible by 4
    float xv = X[row * 64 + c];
    if (relu_in) xv = fmaxf(xv, 0.0f);
    Xs[r * 64 + c] = xv;
    __syncthreads();

    float acc = 0.0f;
#pragma unroll
    for (int k = 0; k < 64; ++k)
        acc = fmaf(Xs[r * 64 + k], Ws[k * 64 + c], acc);

    Hout[row * 64 + c] = acc;
    float di = dinv[row];
    Agg[row * 64 + c] = di * di * acc + bias[c];
}

// ---------------------------------------------------------------------------
// Edge scatter: one wave per edge (64 lanes = 64 features)
// ---------------------------------------------------------------------------
__global__ __launch_bounds__(256) void scatter_edges(
        const int* __restrict__ src, const int* __restrict__ dst,
        const float* __restrict__ norm, const float* __restrict__ H,
        float* __restrict__ Agg) {
    int t = blockIdx.x * 256 + threadIdx.x;
    int e = t >> 6;
    int f = t & 63;
    if (e >= EE) return;
    float v = norm[e] * H[src[e] * 64 + f];
    atomicAdd(&Agg[dst[e] * 64 + f], v);
}

// ---------------------------------------------------------------------------
// Mean pool (batch is sorted): run-length local accumulate, flush per segment
// block = 256 threads = 4 sub-groups x 64 features; each sub-group walks 64
// contiguous nodes.
// ---------------------------------------------------------------------------
__global__ __launch_bounds__(256) void pool_kernel(
        const float* __restrict__ H, const int* __restrict__ batch,
        float* __restrict__ pooled, float* __restrict__ cnt) {
    int tid = threadIdx.x;
    int f = tid & 63, sub = tid >> 6;
    int base = blockIdx.x * 256 + sub * 64;
    float acc = 0.0f;
    int cur = -1, count = 0;
    for (int i = 0; i < 64; ++i) {
        int n = base + i;
        if (n >= NN) break;
        int g = batch[n];
        if (g != cur) {
            if (cur >= 0) {
                atomicAdd(&pooled[cur * 64 + f], acc);
                if (f == 0) atomicAdd(&cnt[cur], (float)count);
            }
            cur = g; acc = 0.0f; count = 0;
        }
        acc += H[n * 64 + f];
        ++count;
    }
    if (cur >= 0) {
        atomicAdd(&pooled[cur * 64 + f], acc);
        if (f == 0) atomicAdd(&cnt[cur], (float)count);
    }
}

// ---------------------------------------------------------------------------
// out[b][c] = (pooled_sum[b]/max(cnt,1)) @ Wl + bl    (one block, 512 threads)
// ---------------------------------------------------------------------------
__global__ __launch_bounds__(512) void final_linear(
        const float* __restrict__ pooled, const float* __restrict__ cnt,
        const float* __restrict__ Wl, const float* __restrict__ bl,
        float* __restrict__ out) {
    int t = threadIdx.x;            // 512 = 256 graphs x 2 classes
    int b = t >> 1, c = t & 1;
    float inv = 1.0f / fmaxf(cnt[b], 1.0f);
    float acc = 0.0f;
#pragma unroll
    for (int f = 0; f < 64; ++f)
        acc += pooled[b * 64 + f] * Wl[f * 2 + c];
    out[t] = acc * inv + bl[c];
}

// ---------------------------------------------------------------------------
static inline size_t align256(size_t x) { return (x + 255) & ~size_t(255); }

extern "C" void kernel_launch(void* const* d_in, const int* in_sizes, int n_in,
                              void* d_out, int out_size, void* d_ws, size_t ws_size,
                              hipStream_t stream) {
    const float* x  = (const float*)d_in[0];
    const int*  eraw = (const int*)d_in[1];
    const int*  braw = (const int*)d_in[2];
    const float* W1 = (const float*)d_in[3];
    const float* b1 = (const float*)d_in[4];
    const float* W2 = (const float*)d_in[5];
    const float* b2 = (const float*)d_in[6];
    const float* W3 = (const float*)d_in[7];
    const float* b3 = (const float*)d_in[8];
    const float* Wl = (const float*)d_in[9];
    const float* bl = (const float*)d_in[10];
    float* out = (float*)d_out;

    char* ws = (char*)d_ws;
    size_t off = 0;
    int*   src32   = (int*)(ws + off);  off = align256(off + (size_t)EE * 4);
    int*   dst32   = (int*)(ws + off);  off = align256(off + (size_t)EE * 4);
    int*   batch32 = (int*)(ws + off);  off = align256(off + (size_t)NN * 4);
    int*   flag    = (int*)(ws + off);  off = align256(off + 256);
    float* deg     = (float*)(ws + off); off = align256(off + (size_t)NN * 4);
    float* dinv    = (float*)(ws + off); off = align256(off + (size_t)NN * 4);
    float* nrm     = (float*)(ws + off); off = align256(off + (size_t)EE * 4);
    float* h       = (float*)(ws + off); off = align256(off + (size_t)NN * HH * 4);
    float* aggA    = (float*)(ws + off); off = align256(off + (size_t)NN * HH * 4);
    float* aggB    = (float*)(ws + off); off = align256(off + (size_t)NN * HH * 4);
    float* pooled  = (float*)(ws + off); off = align256(off + (size_t)BB * HH * 4);
    float* cnt     = (float*)(ws + off); off = align256(off + (size_t)BB * 4);

    const int eBlocks = (EE + 255) / 256;
    const int nBlocks = (NN + 255) / 256;
    const int sBlocks = (int)(((size_t)EE * 64 + 255) / 256);
    const int gBlocks = NN / 4;

    // 0) canonicalize indices
    detect_i64<<<1, 256, 0, stream>>>(eraw, flag);
    convert_edges<<<eBlocks, 256, 0, stream>>>(eraw, src32, dst32, flag);
    convert_batch<<<nBlocks, 256, 0, stream>>>(braw, batch32, flag);

    // 1) degree / norm
    hipMemsetAsync(deg, 0, (size_t)NN * 4, stream);
    deg_kernel<<<eBlocks, 256, 0, stream>>>(dst32, deg);
    dinv_kernel<<<nBlocks, 256, 0, stream>>>(deg, dinv);
    norm_kernel<<<eBlocks, 256, 0, stream>>>(src32, dst32, dinv, nrm);

    // 2) layer 1: x -> aggA
    gemm_init<<<gBlocks, 256, 0, stream>>>(x, W1, b1, dinv, h, aggA, 0);
    scatter_edges<<<sBlocks, 256, 0, stream>>>(src32, dst32, nrm, h, aggA);

    // 3) layer 2: relu(aggA) -> aggB
    gemm_init<<<gBlocks, 256, 0, stream>>>(aggA, W2, b2, dinv, h, aggB, 1);
    scatter_edges<<<sBlocks, 256, 0, stream>>>(src32, dst32, nrm, h, aggB);

    // 4) layer 3: relu(aggB) -> aggA
    gemm_init<<<gBlocks, 256, 0, stream>>>(aggB, W3, b3, dinv, h, aggA, 1);
    scatter_edges<<<sBlocks, 256, 0, stream>>>(src32, dst32, nrm, h, aggA);

    // 5) pool + classifier
    hipMemsetAsync(pooled, 0, (size_t)BB * HH * 4, stream);
    hipMemsetAsync(cnt, 0, (size_t)BB * 4, stream);
    pool_kernel<<<nBlocks, 256, 0, stream>>>(aggA, batch32, pooled, cnt);
    final_linear<<<1, 512, 0, stream>>>(pooled, cnt, Wl, bl, out);
}

// Round 2
// 578.567 us; speedup vs baseline: 1.9270x; 1.9270x over previous
//
#include <hip/hip_runtime.h>

#define NN 100000
#define EE 1250000
#define HH 64
#define BB 256
#define CC 2
#define NBLK 391   // ceil(NN/256)

// ---------------------------------------------------------------------------
// Index dtype canonicalization (int64 vs int32 detection on device)
// ---------------------------------------------------------------------------
__global__ void detect_i64(const int* __restrict__ raw, int* __restrict__ flag) {
    __shared__ int nonzero;
    if (threadIdx.x == 0) nonzero = 0;
    __syncthreads();
    int any = 0;
#pragma unroll
    for (int i = 0; i < 4; ++i) {
        int idx = 2 * (threadIdx.x + i * 256) + 1;   // odd words, safe in both layouts
        if (raw[idx] != 0) any = 1;
    }
    if (any) atomicOr(&nonzero, 1);
    __syncthreads();
    if (threadIdx.x == 0) *flag = nonzero ? 0 : 1;   // 1 => int64
}

__global__ void convert_edges(const int* __restrict__ raw, int* __restrict__ src,
                              int* __restrict__ dst, const int* __restrict__ flag) {
    int e = blockIdx.x * 256 + threadIdx.x;
    if (e >= EE) return;
    int f = *flag;
    src[e] = f ? raw[2 * e]        : raw[e];
    dst[e] = f ? raw[2 * (EE + e)] : raw[EE + e];
}

__global__ void convert_batch(const int* __restrict__ raw, int* __restrict__ out,
                              const int* __restrict__ flag) {
    int n = blockIdx.x * 256 + threadIdx.x;
    if (n >= NN) return;
    out[n] = (*flag) ? raw[2 * n] : raw[n];
}

// ---------------------------------------------------------------------------
// CSR build: degree count -> exclusive scan -> counting sort
// ---------------------------------------------------------------------------
__global__ void count_kernel(const int* __restrict__ dst, int* __restrict__ degi) {
    int e = blockIdx.x * 256 + threadIdx.x;
    if (e < EE) atomicAdd(&degi[dst[e]], 1);
}

__global__ void dinv_kernel(const int* __restrict__ degi, float* __restrict__ dinv) {
    int n = blockIdx.x * 256 + threadIdx.x;
    if (n < NN) dinv[n] = rsqrtf((float)degi[n] + 1.0f);
}

// block-level inclusive scan (Hillis-Steele in LDS), write partial exclusive
__global__ __launch_bounds__(256) void scan1(const int* __restrict__ degi,
                                             int* __restrict__ row,
                                             int* __restrict__ bsum) {
    __shared__ int s[256];
    int tid = threadIdx.x;
    int n = blockIdx.x * 256 + tid;
    int v = (n < NN) ? degi[n] : 0;
    int x = v;
    s[tid] = x;
    __syncthreads();
    for (int off = 1; off < 256; off <<= 1) {
        int t = (tid >= off) ? s[tid - off] : 0;
        __syncthreads();
        x += t;
        s[tid] = x;
        __syncthreads();
    }
    if (n < NN) row[n] = x - v;             // partial exclusive
    if (tid == 255) bsum[blockIdx.x] = x;   // block total
}

// exclusive scan of 391 block sums in one block
__global__ __launch_bounds__(512) void scan2(int* __restrict__ bsum) {
    __shared__ int s[512];
    int tid = threadIdx.x;
    int v = (tid < NBLK) ? bsum[tid] : 0;
    int x = v;
    s[tid] = x;
    __syncthreads();
    for (int off = 1; off < 512; off <<= 1) {
        int t = (tid >= off) ? s[tid - off] : 0;
        __syncthreads();
        x += t;
        s[tid] = x;
        __syncthreads();
    }
    if (tid < NBLK) bsum[tid] = x - v;      // exclusive
}

__global__ void scan3(int* __restrict__ row, const int* __restrict__ bsum) {
    int n = blockIdx.x * 256 + threadIdx.x;
    if (n < NN) row[n] += bsum[blockIdx.x];
    if (n == 0) row[NN] = EE;
}

// counting sort: esort[pos] = (src, bits(norm)), grouped by dst
__global__ void fill_kernel(const int* __restrict__ src, const int* __restrict__ dst,
                            const float* __restrict__ dinv,
                            const int* __restrict__ row, int* __restrict__ fill,
                            int2* __restrict__ esort) {
    int e = blockIdx.x * 256 + threadIdx.x;
    if (e >= EE) return;
    int s = src[e], d = dst[e];
    int pos = row[d] + atomicAdd(&fill[d], 1);
    float nm = dinv[s] * dinv[d];
    esort[pos] = make_int2(s, __float_as_int(nm));
}

// ---------------------------------------------------------------------------
// h = (relu?)X @ W   (block = 4 rows x 64 cols, W in LDS)
// ---------------------------------------------------------------------------
__global__ __launch_bounds__(256) void gemm_kernel(
        const float* __restrict__ X, const float* __restrict__ W,
        float* __restrict__ Hout, int relu_in) {
    __shared__ float Ws[64 * 64];
    __shared__ float Xs[4 * 64];
    int tid = threadIdx.x;
    for (int i = tid; i < 64 * 64; i += 256) Ws[i] = W[i];

    int r = tid >> 6, c = tid & 63;
    int row = blockIdx.x * 4 + r;
    float xv = X[row * 64 + c];
    if (relu_in) xv = fmaxf(xv, 0.0f);
    Xs[r * 64 + c] = xv;
    __syncthreads();

    float acc = 0.0f;
#pragma unroll
    for (int k = 0; k < 64; ++k)
        acc = fmaf(Xs[r * 64 + k], Ws[k * 64 + c], acc);

    Hout[row * 64 + c] = acc;
}

// ---------------------------------------------------------------------------
// Node-parallel gather: one wave per node (64 lanes = 64 features).
// Agg[n] = sum_{e in CSR[n]} norm_e * H[src_e] + dinv[n]^2 * H[n] + bias
// ---------------------------------------------------------------------------
__global__ __launch_bounds__(256) void gather_kernel(
        const int* __restrict__ row, const int2* __restrict__ esort,
        const float* __restrict__ H, const float* __restrict__ dinv,
        const float* __restrict__ bias, float* __restrict__ Agg) {
    int tid = threadIdx.x;
    int f = tid & 63, w = tid >> 6;
    int n = blockIdx.x * 4 + w;
    if (n >= NN) return;
    int beg = row[n], end = row[n + 1];

    float acc = 0.0f;
    for (int base = beg; base < end; base += 64) {
        int cnt = end - base; if (cnt > 64) cnt = 64;
        int2 meta = (f < cnt) ? esort[base + f] : make_int2(0, 0);
        // software-pipelined broadcast walk
        int   scur = __shfl(meta.x, 0, 64);
        float wcur = __int_as_float(__shfl(meta.y, 0, 64));
        float hcur = H[(size_t)scur * 64 + f];
        for (int j = 1; j < cnt; ++j) {
            int   snx = __shfl(meta.x, j, 64);
            float wnx = __int_as_float(__shfl(meta.y, j, 64));
            float hnx = H[(size_t)snx * 64 + f];
            acc = fmaf(wcur, hcur, acc);
            scur = snx; wcur = wnx; hcur = hnx;
        }
        acc = fmaf(wcur, hcur, acc);
    }
    float di = dinv[n];
    float hv = H[(size_t)n * 64 + f];
    Agg[(size_t)n * 64 + f] = acc + di * di * hv + bias[f];
}

// ---------------------------------------------------------------------------
// Mean pool (batch sorted) + final linear
// ---------------------------------------------------------------------------
__global__ __launch_bounds__(256) void pool_kernel(
        const float* __restrict__ H, const int* __restrict__ batch,
        float* __restrict__ pooled, float* __restrict__ cnt) {
    int tid = threadIdx.x;
    int f = tid & 63, sub = tid >> 6;
    int base = blockIdx.x * 256 + sub * 64;
    float acc = 0.0f;
    int cur = -1, count = 0;
    for (int i = 0; i < 64; ++i) {
        int n = base + i;
        if (n >= NN) break;
        int g = batch[n];
        if (g != cur) {
            if (cur >= 0) {
                atomicAdd(&pooled[cur * 64 + f], acc);
                if (f == 0) atomicAdd(&cnt[cur], (float)count);
            }
            cur = g; acc = 0.0f; count = 0;
        }
        acc += H[(size_t)n * 64 + f];
        ++count;
    }
    if (cur >= 0) {
        atomicAdd(&pooled[cur * 64 + f], acc);
        if (f == 0) atomicAdd(&cnt[cur], (float)count);
    }
}

__global__ __launch_bounds__(512) void final_linear(
        const float* __restrict__ pooled, const float* __restrict__ cnt,
        const float* __restrict__ Wl, const float* __restrict__ bl,
        float* __restrict__ out) {
    int t = threadIdx.x;            // 512 = 256 graphs x 2 classes
    int b = t >> 1, c = t & 1;
    float inv = 1.0f / fmaxf(cnt[b], 1.0f);
    float acc = 0.0f;
#pragma unroll
    for (int fi = 0; fi < 64; ++fi)
        acc += pooled[b * 64 + fi] * Wl[fi * 2 + c];
    out[t] = acc * inv + bl[c];
}

// ---------------------------------------------------------------------------
static inline size_t align256(size_t x) { return (x + 255) & ~size_t(255); }

extern "C" void kernel_launch(void* const* d_in, const int* in_sizes, int n_in,
                              void* d_out, int out_size, void* d_ws, size_t ws_size,
                              hipStream_t stream) {
    const float* x  = (const float*)d_in[0];
    const int*  eraw = (const int*)d_in[1];
    const int*  braw = (const int*)d_in[2];
    const float* W1 = (const float*)d_in[3];
    const float* b1 = (const float*)d_in[4];
    const float* W2 = (const float*)d_in[5];
    const float* b2 = (const float*)d_in[6];
    const float* W3 = (const float*)d_in[7];
    const float* b3 = (const float*)d_in[8];
    const float* Wl = (const float*)d_in[9];
    const float* bl = (const float*)d_in[10];
    float* out = (float*)d_out;

    char* ws = (char*)d_ws;
    size_t off = 0;
    int*   src32   = (int*)(ws + off);   off = align256(off + (size_t)EE * 4);
    int*   dst32   = (int*)(ws + off);   off = align256(off + (size_t)EE * 4);
    int*   batch32 = (int*)(ws + off);   off = align256(off + (size_t)NN * 4);
    int*   flag    = (int*)(ws + off);   off = align256(off + 256);
    int*   degi    = (int*)(ws + off);   off = align256(off + (size_t)NN * 4);
    float* dinv    = (float*)(ws + off); off = align256(off + (size_t)NN * 4);
    int*   row     = (int*)(ws + off);   off = align256(off + (size_t)(NN + 1) * 4);
    int*   bsum    = (int*)(ws + off);   off = align256(off + (size_t)NBLK * 4);
    int*   fillc   = (int*)(ws + off);   off = align256(off + (size_t)NN * 4);
    int2*  esort   = (int2*)(ws + off);  off = align256(off + (size_t)EE * 8);
    float* h       = (float*)(ws + off); off = align256(off + (size_t)NN * HH * 4);
    float* aggA    = (float*)(ws + off); off = align256(off + (size_t)NN * HH * 4);
    float* aggB    = (float*)(ws + off); off = align256(off + (size_t)NN * HH * 4);
    float* pooled  = (float*)(ws + off); off = align256(off + (size_t)BB * HH * 4);
    float* cnt     = (float*)(ws + off); off = align256(off + (size_t)BB * 4);

    const int eBlocks = (EE + 255) / 256;
    const int nBlocks = NBLK;
    const int gBlocks = NN / 4;   // gemm + gather: 4 nodes / block

    // 0) canonicalize indices
    detect_i64<<<1, 256, 0, stream>>>(eraw, flag);
    convert_edges<<<eBlocks, 256, 0, stream>>>(eraw, src32, dst32, flag);
    convert_batch<<<nBlocks, 256, 0, stream>>>(braw, batch32, flag);

    // 1) CSR build
    hipMemsetAsync(degi, 0, (size_t)NN * 4, stream);
    count_kernel<<<eBlocks, 256, 0, stream>>>(dst32, degi);
    dinv_kernel<<<nBlocks, 256, 0, stream>>>(degi, dinv);
    scan1<<<nBlocks, 256, 0, stream>>>(degi, row, bsum);
    scan2<<<1, 512, 0, stream>>>(bsum);
    scan3<<<nBlocks, 256, 0, stream>>>(row, bsum);
    hipMemsetAsync(fillc, 0, (size_t)NN * 4, stream);
    fill_kernel<<<eBlocks, 256, 0, stream>>>(src32, dst32, dinv, row, fillc, esort);

    // 2) three GCN layers (gemm -> gather)
    gemm_kernel<<<gBlocks, 256, 0, stream>>>(x, W1, h, 0);
    gather_kernel<<<gBlocks, 256, 0, stream>>>(row, esort, h, dinv, b1, aggA);

    gemm_kernel<<<gBlocks, 256, 0, stream>>>(aggA, W2, h, 1);
    gather_kernel<<<gBlocks, 256, 0, stream>>>(row, esort, h, dinv, b2, aggB);

    gemm_kernel<<<gBlocks, 256, 0, stream>>>(aggB, W3, h, 1);
    gather_kernel<<<gBlocks, 256, 0, stream>>>(row, esort, h, dinv, b3, aggA);

    // 3) pool + classifier
    hipMemsetAsync(pooled, 0, (size_t)BB * HH * 4, stream);
    hipMemsetAsync(cnt, 0, (size_t)BB * 4, stream);
    pool_kernel<<<nBlocks, 256, 0, stream>>>(aggA, batch32, pooled, cnt);
    final_linear<<<1, 512, 0, stream>>>(pooled, cnt, Wl, bl, out);
}

// Round 3
// 381.129 us; speedup vs baseline: 2.9253x; 1.5180x over previous
//
#include <hip/hip_runtime.h>

#define NN 100000
#define EE 1250000
#define HH 64
#define BB 256
#define CC 2
#define NBLK 391            // ceil(NN/256)
#define GBLK 2048           // persistent gather/gemm blocks
#define NWAVE (GBLK * 4)    // waves in persistent grid

__device__ __forceinline__ float lanebcast(float v, int k) {
    return __int_as_float(__builtin_amdgcn_readlane(__float_as_int(v), k));
}

// ---------------------------------------------------------------------------
// Index dtype detection (int64 vs int32): int64 values < 2^31 -> odd words 0
// ---------------------------------------------------------------------------
__global__ void detect_i64(const int* __restrict__ raw, int* __restrict__ flag) {
    __shared__ int nonzero;
    if (threadIdx.x == 0) nonzero = 0;
    __syncthreads();
    int any = 0;
#pragma unroll
    for (int i = 0; i < 4; ++i) {
        int idx = 2 * (threadIdx.x + i * 256) + 1;
        if (raw[idx] != 0) any = 1;
    }
    if (any) atomicOr(&nonzero, 1);
    __syncthreads();
    if (threadIdx.x == 0) *flag = nonzero ? 0 : 1;   // 1 => int64
}

// ---------------------------------------------------------------------------
// CSR build (reads raw edge index directly; flag selects stride)
// ---------------------------------------------------------------------------
__global__ void count_kernel(const int* __restrict__ raw, const int* __restrict__ flag,
                             int* __restrict__ degi) {
    int e = blockIdx.x * 256 + threadIdx.x;
    if (e >= EE) return;
    int d = (*flag) ? raw[2 * (EE + e)] : raw[EE + e];
    atomicAdd(&degi[d], 1);
}

// block scan + fused dinv
__global__ __launch_bounds__(256) void scan1(const int* __restrict__ degi,
                                             int* __restrict__ row,
                                             int* __restrict__ bsum,
                                             float* __restrict__ dinv) {
    __shared__ int s[256];
    int tid = threadIdx.x;
    int n = blockIdx.x * 256 + tid;
    int v = (n < NN) ? degi[n] : 0;
    int x = v;
    s[tid] = x;
    __syncthreads();
    for (int off = 1; off < 256; off <<= 1) {
        int t = (tid >= off) ? s[tid - off] : 0;
        __syncthreads();
        x += t;
        s[tid] = x;
        __syncthreads();
    }
    if (n < NN) {
        row[n] = x - v;
        dinv[n] = rsqrtf((float)v + 1.0f);
    }
    if (tid == 255) bsum[blockIdx.x] = x;
}

__global__ __launch_bounds__(512) void scan2(int* __restrict__ bsum) {
    __shared__ int s[512];
    int tid = threadIdx.x;
    int v = (tid < NBLK) ? bsum[tid] : 0;
    int x = v;
    s[tid] = x;
    __syncthreads();
    for (int off = 1; off < 512; off <<= 1) {
        int t = (tid >= off) ? s[tid - off] : 0;
        __syncthreads();
        x += t;
        s[tid] = x;
        __syncthreads();
    }
    if (tid < NBLK) bsum[tid] = x - v;
}

__global__ void scan3(int* __restrict__ row, const int* __restrict__ bsum) {
    int n = blockIdx.x * 256 + threadIdx.x;
    if (n < NN) row[n] += bsum[blockIdx.x];
    if (n == 0) row[NN] = EE;
}

__global__ void fill_kernel(const int* __restrict__ raw, const int* __restrict__ flag,
                            const float* __restrict__ dinv,
                            const int* __restrict__ row, int* __restrict__ fill,
                            int2* __restrict__ esort) {
    int e = blockIdx.x * 256 + threadIdx.x;
    if (e >= EE) return;
    int flg = *flag;
    int s = flg ? raw[2 * e]        : raw[e];
    int d = flg ? raw[2 * (EE + e)] : raw[EE + e];
    int pos = row[d] + atomicAdd(&fill[d], 1);
    float nm = dinv[s] * dinv[d];
    esort[pos] = make_int2(s, __float_as_int(nm));
}

// ---------------------------------------------------------------------------
// Persistent register-W GEMM: one wave per row, W column in 64 VGPRs
// ---------------------------------------------------------------------------
__global__ __launch_bounds__(256) void gemm_reg(const float* __restrict__ X,
                                                const float* __restrict__ W,
                                                float* __restrict__ Hout) {
    int lane = threadIdx.x & 63;
    int gw = (blockIdx.x * 256 + threadIdx.x) >> 6;
    float Wreg[64];
#pragma unroll
    for (int k = 0; k < 64; ++k) Wreg[k] = W[k * 64 + lane];
    for (int n = gw; n < NN; n += NWAVE) {
        float xv = X[(size_t)n * 64 + lane];
        float a0 = 0.f, a1 = 0.f;
#pragma unroll
        for (int k = 0; k < 64; k += 2) {
            a0 = fmaf(lanebcast(xv, k),     Wreg[k],     a0);
            a1 = fmaf(lanebcast(xv, k + 1), Wreg[k + 1], a1);
        }
        Hout[(size_t)n * 64 + lane] = a0 + a1;
    }
}

// ---------------------------------------------------------------------------
// Gather, 8-deep pipelined; FUSE=1 additionally computes relu(agg) @ Wn
// One wave per node, persistent grid-stride.
// ---------------------------------------------------------------------------
template <int FUSE>
__global__ __launch_bounds__(256) void gather_kernel(
        const int* __restrict__ row, const int2* __restrict__ esort,
        const float* __restrict__ H, const float* __restrict__ dinv,
        const float* __restrict__ bias, const float* __restrict__ Wn,
        float* __restrict__ Out) {
    int lane = threadIdx.x & 63;
    int gw = (blockIdx.x * 256 + threadIdx.x) >> 6;

    float Wreg[FUSE ? 64 : 1];
    if constexpr (FUSE) {
#pragma unroll
        for (int k = 0; k < 64; ++k) Wreg[k] = Wn[k * 64 + lane];
    }
    float bv = bias[lane];

    for (int n = gw; n < NN; n += NWAVE) {
        int beg = row[n], end = row[n + 1];
        float acc = 0.0f;
        for (int base = beg; base < end; base += 64) {
            int cnt = end - base; if (cnt > 64) cnt = 64;
            // lanes >= cnt hold (src=0, w=0): padded edges add 0.0 and read
            // the L1-hot row 0
            int2 meta = (lane < cnt) ? esort[base + lane] : make_int2(0, 0);
            int cntp = (cnt + 7) & ~7;
            for (int j = 0; j < cntp; j += 8) {
                float hv[8], wv[8];
#pragma unroll
                for (int i = 0; i < 8; ++i) {
                    int s = __shfl(meta.x, j + i, 64);
                    wv[i] = __int_as_float(__shfl(meta.y, j + i, 64));
                    hv[i] = H[(size_t)s * 64 + lane];
                }
#pragma unroll
                for (int i = 0; i < 8; ++i) acc = fmaf(wv[i], hv[i], acc);
            }
        }
        float di = dinv[n];
        float agg = acc + di * di * H[(size_t)n * 64 + lane] + bv;
        if constexpr (FUSE) {
            float av = fmaxf(agg, 0.0f);            // relu
            float a0 = 0.f, a1 = 0.f;
#pragma unroll
            for (int k = 0; k < 64; k += 2) {
                a0 = fmaf(lanebcast(av, k),     Wreg[k],     a0);
                a1 = fmaf(lanebcast(av, k + 1), Wreg[k + 1], a1);
            }
            Out[(size_t)n * 64 + lane] = a0 + a1;   // next layer's pre-h
        } else {
            Out[(size_t)n * 64 + lane] = agg;
        }
    }
}

// ---------------------------------------------------------------------------
// Mean pool (batch sorted, reads raw batch vector) + final linear
// ---------------------------------------------------------------------------
__global__ __launch_bounds__(256) void pool_kernel(
        const float* __restrict__ H, const int* __restrict__ braw,
        const int* __restrict__ flag,
        float* __restrict__ pooled, float* __restrict__ cnt) {
    int tid = threadIdx.x;
    int f = tid & 63, sub = tid >> 6;
    int flg = *flag;
    int base = blockIdx.x * 256 + sub * 64;
    float acc = 0.0f;
    int cur = -1, count = 0;
    for (int i = 0; i < 64; ++i) {
        int n = base + i;
        if (n >= NN) break;
        int g = flg ? braw[2 * n] : braw[n];
        if (g != cur) {
            if (cur >= 0) {
                atomicAdd(&pooled[cur * 64 + f], acc);
                if (f == 0) atomicAdd(&cnt[cur], (float)count);
            }
            cur = g; acc = 0.0f; count = 0;
        }
        acc += H[(size_t)n * 64 + f];
        ++count;
    }
    if (cur >= 0) {
        atomicAdd(&pooled[cur * 64 + f], acc);
        if (f == 0) atomicAdd(&cnt[cur], (float)count);
    }
}

__global__ __launch_bounds__(512) void final_linear(
        const float* __restrict__ pooled, const float* __restrict__ cnt,
        const float* __restrict__ Wl, const float* __restrict__ bl,
        float* __restrict__ out) {
    int t = threadIdx.x;            // 512 = 256 graphs x 2 classes
    int b = t >> 1, c = t & 1;
    float inv = 1.0f / fmaxf(cnt[b], 1.0f);
    float acc = 0.0f;
#pragma unroll
    for (int fi = 0; fi < 64; ++fi)
        acc += pooled[b * 64 + fi] * Wl[fi * 2 + c];
    out[t] = acc * inv + bl[c];
}

// ---------------------------------------------------------------------------
static inline size_t align256(size_t x) { return (x + 255) & ~size_t(255); }

extern "C" void kernel_launch(void* const* d_in, const int* in_sizes, int n_in,
                              void* d_out, int out_size, void* d_ws, size_t ws_size,
                              hipStream_t stream) {
    const float* x   = (const float*)d_in[0];
    const int*  eraw = (const int*)d_in[1];
    const int*  braw = (const int*)d_in[2];
    const float* W1 = (const float*)d_in[3];
    const float* b1 = (const float*)d_in[4];
    const float* W2 = (const float*)d_in[5];
    const float* b2 = (const float*)d_in[6];
    const float* W3 = (const float*)d_in[7];
    const float* b3 = (const float*)d_in[8];
    const float* Wl = (const float*)d_in[9];
    const float* bl = (const float*)d_in[10];
    float* out = (float*)d_out;

    char* ws = (char*)d_ws;
    size_t off = 0;
    int*   flag   = (int*)(ws + off);   off = align256(off + 256);
    // --- contiguous zero region: degi, fillc, pooled, cnt ---
    size_t zoff = off;
    int*   degi   = (int*)(ws + off);   off = align256(off + (size_t)NN * 4);
    int*   fillc  = (int*)(ws + off);   off = align256(off + (size_t)NN * 4);
    float* pooled = (float*)(ws + off); off = align256(off + (size_t)BB * HH * 4);
    float* cnt    = (float*)(ws + off); off = align256(off + (size_t)BB * 4);
    size_t zlen = off - zoff;
    // --- rest ---
    float* dinv   = (float*)(ws + off); off = align256(off + (size_t)NN * 4);
    int*   row    = (int*)(ws + off);   off = align256(off + (size_t)(NN + 1) * 4);
    int*   bsum   = (int*)(ws + off);   off = align256(off + (size_t)NBLK * 4);
    int2*  esort  = (int2*)(ws + off);  off = align256(off + (size_t)EE * 8);
    float* hA     = (float*)(ws + off); off = align256(off + (size_t)NN * HH * 4);
    float* hB     = (float*)(ws + off); off = align256(off + (size_t)NN * HH * 4);
    float* hC     = (float*)(ws + off); off = align256(off + (size_t)NN * HH * 4);

    const int eBlocks = (EE + 255) / 256;

    detect_i64<<<1, 256, 0, stream>>>(eraw, flag);
    hipMemsetAsync(ws + zoff, 0, zlen, stream);

    // CSR build
    count_kernel<<<eBlocks, 256, 0, stream>>>(eraw, flag, degi);
    scan1<<<NBLK, 256, 0, stream>>>(degi, row, bsum, dinv);
    scan2<<<1, 512, 0, stream>>>(bsum);
    scan3<<<NBLK, 256, 0, stream>>>(row, bsum);
    fill_kernel<<<eBlocks, 256, 0, stream>>>(eraw, flag, dinv, row, fillc, esort);

    // layer pipeline: gemm1 -> gather(+gemm2) -> gather(+gemm3) -> gather
    gemm_reg<<<GBLK, 256, 0, stream>>>(x, W1, hA);
    gather_kernel<1><<<GBLK, 256, 0, stream>>>(row, esort, hA, dinv, b1, W2, hB);
    gather_kernel<1><<<GBLK, 256, 0, stream>>>(row, esort, hB, dinv, b2, W3, hA);
    gather_kernel<0><<<GBLK, 256, 0, stream>>>(row, esort, hA, dinv, b3, nullptr, hC);

    // pool + classifier
    pool_kernel<<<NBLK, 256, 0, stream>>>(hC, braw, flag, pooled, cnt);
    final_linear<<<1, 512, 0, stream>>>(pooled, cnt, Wl, bl, out);
}